// Round 1
// 386.946 us; speedup vs baseline: 1.0592x; 1.0592x over previous
//
#include <hip/hip_runtime.h>
#include <stdint.h>

#define DIMN 1024
#define NH 16
#define HD 64
#define FFN 4096
#define BBATCH 2
#define SSEQ 2048
#define MROWS (BBATCH*SSEQ)   // 4096

typedef __bf16 bf16;
typedef __bf16 bf16x8 __attribute__((ext_vector_type(8)));
typedef __bf16 bf16x4 __attribute__((ext_vector_type(4)));
typedef float f32x4 __attribute__((ext_vector_type(4)));
typedef float f32x16 __attribute__((ext_vector_type(16)));
typedef uint32_t u32x4 __attribute__((ext_vector_type(4)));

#define AS1 __attribute__((address_space(1)))
#define AS3 __attribute__((address_space(3)))

__device__ __forceinline__ void gload16(const bf16* g, bf16* l) {
  __builtin_amdgcn_global_load_lds((AS1 const void*)g, (AS3 void*)l, 16, 0, 0);
}

__device__ __forceinline__ uint32_t pkbf(float a, float b) {
  union { bf16 h[2]; uint32_t u; } x;
  x.h[0] = (bf16)a; x.h[1] = (bf16)b;
  return x.u;
}

// ---------------- rope table: tab[s*64 + d] = cos, tab[s*64+32+d] = sin ----
__global__ void rope_table_kernel(float* __restrict__ tab) {
  int i = blockIdx.x * blockDim.x + threadIdx.x;   // 0..65535
  int s = i >> 5, d = i & 31;
  float invf = exp2f(-(float)d * 0.4152410118609203f);
  float fr = (float)s * invf;
  tab[s*64 + d]      = cosf(fr);
  tab[s*64 + 32 + d] = sinf(fr);
}

// ---------------- f32 -> bf16 cast (vector x4) -----------------------------
__global__ void cast_f32_bf16(const float* __restrict__ in, bf16* __restrict__ out, int n4) {
  int i = blockIdx.x * blockDim.x + threadIdx.x;
  if (i < n4) {
    f32x4 v = ((const f32x4*)in)[i];
    bf16x4 o = {(bf16)v.x, (bf16)v.y, (bf16)v.z, (bf16)v.w};
    ((bf16x4*)out)[i] = o;
  }
}

// ---------------- transpose + cast: f32 [R][C] -> bf16 [C][R] --------------
__global__ __launch_bounds__(256) void transpose_cast_f32_bf16(
    const float* __restrict__ in, bf16* __restrict__ out, int R, int C) {
  __shared__ float t[32][33];
  int bx = blockIdx.x, by = blockIdx.y;
  int x = threadIdx.x, y = threadIdx.y;     // (32, 8)
  #pragma unroll
  for (int j = 0; j < 4; ++j) {
    int r = by*32 + y*4 + j;
    t[y*4+j][x] = in[(size_t)r*C + bx*32 + x];
  }
  __syncthreads();
  #pragma unroll
  for (int j = 0; j < 4; ++j) {
    int c = bx*32 + y*4 + j;
    out[(size_t)c*R + by*32 + x] = (bf16)t[x][y*4+j];
  }
}

// ---------------- RMSNorm over (sum of NP partials + resid) ----------------
// parts: NP contiguous f32 [MROWS][DIMN] planes (stride MROWS*DIMN floats)
template<int NP>
__global__ __launch_bounds__(256) void rmsnorm_sum_kernel(
    const float* __restrict__ parts, const float* __restrict__ resid,
    const float* __restrict__ sc,
    float* __restrict__ outf, bf16* __restrict__ outb) {
  int row = blockIdx.x;
  int tid = threadIdx.x;
  size_t off = (size_t)row * DIMN;
  f32x4 v = ((const f32x4*)(resid + off))[tid];
  #pragma unroll
  for (int p = 0; p < NP; ++p) {
    f32x4 a = ((const f32x4*)(parts + (size_t)p * MROWS * DIMN + off))[tid];
    v.x += a.x; v.y += a.y; v.z += a.z; v.w += a.w;
  }
  float ss = v.x*v.x + v.y*v.y + v.z*v.z + v.w*v.w;
  #pragma unroll
  for (int m = 1; m < 64; m <<= 1) ss += __shfl_xor(ss, m);
  __shared__ float red[4];
  if ((tid & 63) == 0) red[tid >> 6] = ss;
  __syncthreads();
  float tot = red[0] + red[1] + red[2] + red[3];
  float inv = 1.f / (sqrtf(tot) * 0.03125f + 1e-8f);
  f32x4 s4 = ((const f32x4*)sc)[tid];
  f32x4 o = {v.x*s4.x*inv, v.y*s4.y*inv, v.z*s4.z*inv, v.w*s4.w*inv};
  if (outf) ((f32x4*)(outf + off))[tid] = o;
  if (outb) {
    bf16x4 ob = {(bf16)o.x, (bf16)o.y, (bf16)o.z, (bf16)o.w};
    ((bf16x4*)(outb + off))[tid] = ob;
  }
}

// ---------------- GEMM: C[M][N] = A[M][K] * B^T[N][K]  (m97 structure) -----
// Split-K via gridDim.z: block z computes K-chunk [z*KC, (z+1)*KC).
// EPI 0: QKV+rope -> fragment-layout Q/K/V for attention:
//   QF/KF[bh][tile][ds][lane][8]  (tile=token/32, lane=hi*32+ql, d=ds*16+hi*8+j)
//   VF[bh][tile][ks*2+half][lane][8] (kvl=token%32=ks*16+hi*8+j, d=half*32+ql)
// EPI 1: f32 out = acc + resid   (o0=f32 out, a0=f32 resid, both [M][N])
// EPI 2: bf16 out = sigmoid(acc + bias[col])   (o0=bf16 out, a0=f32 bias)
// EPI 3: bf16 out = gate[r][c] * (acc + bias[col]) (o0=bf16, a0=bf16 gate, a1=f32 bias)
// EPI 4: f32 partial: o0[z*M*N + r*N + c] = acc   (split-K, no resid)
template<int EPI>
__global__ void __launch_bounds__(256) gemm_bt(
    const bf16* __restrict__ A, const bf16* __restrict__ B,
    int M, int N, int K,
    void* __restrict__ o0, void* __restrict__ o1, void* __restrict__ o2,
    const void* __restrict__ a0, const void* __restrict__ a1) {
  __shared__ __align__(16) bf16 sh_a[128*32];
  __shared__ __align__(16) bf16 sh_b[128*32];
  const int tid  = threadIdx.x;
  const int lane = tid & 63;
  const int wid  = tid >> 6;

  // XCD-aware swizzle (all our grids have nwg % 8 == 0 -> bijective)
  int gx  = gridDim.x;
  int bid = blockIdx.y * gx + blockIdx.x;
  int nwg = gx * gridDim.y;
  int cpx = nwg >> 3;
  int swz = (bid & 7) * cpx + (bid >> 3);
  int bxi = swz % gx, byi = swz / gx;

  const int m0 = byi * 128, n0 = bxi * 128;
  const int wm = (wid >> 1) * 64, wn = (wid & 1) * 64;

  // split-K chunk
  const int kb = blockIdx.z;
  const int KC = K / (int)gridDim.z;

  f32x4 acc[4][4] = {};

  const bf16* a_base = A + (size_t)m0 * K + (size_t)kb * KC;
  const bf16* b_base = B + (size_t)n0 * K + (size_t)kb * KC;

  for (int k0 = 0; k0 < KC; k0 += 32) {
    __syncthreads();
    #pragma unroll
    for (int i = 0; i < 2; ++i) {
      int idx = i*256 + tid;
      gload16(a_base + (size_t)(idx >> 2)*K + k0 + (idx & 3)*8, &sh_a[idx*8]);
    }
    #pragma unroll
    for (int i = 0; i < 2; ++i) {
      int idx = i*256 + tid;
      gload16(b_base + (size_t)(idx >> 2)*K + k0 + (idx & 3)*8, &sh_b[idx*8]);
    }
    __syncthreads();
    bf16x8 af[4], bfr[4];
    #pragma unroll
    for (int m = 0; m < 4; ++m)
      af[m] = *(const bf16x8*)&sh_a[(wm + m*16 + (lane & 15))*32 + (lane >> 4)*8];
    #pragma unroll
    for (int n = 0; n < 4; ++n)
      bfr[n] = *(const bf16x8*)&sh_b[(wn + n*16 + (lane & 15))*32 + (lane >> 4)*8];
    #pragma unroll
    for (int m = 0; m < 4; ++m)
      #pragma unroll
      for (int n = 0; n < 4; ++n)
        acc[m][n] = __builtin_amdgcn_mfma_f32_16x16x32_bf16(af[m], bfr[n], acc[m][n], 0, 0, 0);
  }

  const int rq = (lane >> 4) * 4;
  const int cl = lane & 15;

  if constexpr (EPI == 0) {
    bf16* q_p = (bf16*)o0; bf16* k_p = (bf16*)o1; bf16* v_p = (bf16*)o2;
    const float* rope = (const float*)a0;
    int sec = (n0 + wn) >> 10;             // 0=q, 1=k, 2=v
    int h   = ((n0 + wn) & 1023) >> 6;
    #pragma unroll
    for (int m = 0; m < 4; ++m) {
      #pragma unroll
      for (int reg = 0; reg < 4; ++reg) {
        int r  = m0 + wm + m*16 + rq + reg;
        int b_ = r >> 11, s_ = r & 2047;
        int tile = s_ >> 5;
        size_t tb = ((size_t)(b_*NH + h) * 64 + tile) * 2048;  // 4KB tile base
        if (sec == 2) {
          int kvl = s_ & 31;
          int ks = kvl >> 4, hiv = (kvl >> 3) & 1, jv = kvl & 7;
          #pragma unroll
          for (int n = 0; n < 4; ++n) {
            int half = n >> 1;
            int qlv  = (n & 1) * 16 + cl;
            v_p[tb + (size_t)(ks*2 + half)*512 + (hiv*32 + qlv)*8 + jv] =
                (bf16)acc[m][n][reg];
          }
        } else {
          int qlt = s_ & 31;
          bf16* dst = (sec == 0 ? q_p : k_p);
          int lo = ((cl >> 3) * 32 + qlt) * 8 + (cl & 7);
          #pragma unroll
          for (int n = 0; n < 2; ++n) {
            int d1 = n*16 + cl;
            float c1 = rope[s_*64 + d1];
            float s1 = rope[s_*64 + 32 + d1];
            float x1 = acc[m][n][reg], x2 = acc[m][n+2][reg];
            dst[tb + (size_t)n*512 + lo]       = (bf16)(x1*c1 - x2*s1);
            dst[tb + (size_t)(n+2)*512 + lo]   = (bf16)(x1*s1 + x2*c1);
          }
        }
      }
    }
  } else if constexpr (EPI == 1) {
    float* op = (float*)o0;
    const float* rp = (const float*)a0;
    #pragma unroll
    for (int m = 0; m < 4; ++m)
      #pragma unroll
      for (int n = 0; n < 4; ++n)
        #pragma unroll
        for (int reg = 0; reg < 4; ++reg) {
          int r = m0 + wm + m*16 + rq + reg;
          int c = n0 + wn + n*16 + cl;
          op[(size_t)r*N + c] = acc[m][n][reg] + rp[(size_t)r*N + c];
        }
  } else if constexpr (EPI == 2) {
    bf16* op = (bf16*)o0;
    const float* bias = (const float*)a0;
    #pragma unroll
    for (int m = 0; m < 4; ++m)
      #pragma unroll
      for (int n = 0; n < 4; ++n)
        #pragma unroll
        for (int reg = 0; reg < 4; ++reg) {
          int r = m0 + wm + m*16 + rq + reg;
          int c = n0 + wn + n*16 + cl;
          float g = acc[m][n][reg] + bias[c];
          op[(size_t)r*N + c] = (bf16)(1.f / (1.f + __expf(-g)));
        }
  } else if constexpr (EPI == 3) {
    bf16* op = (bf16*)o0;
    const bf16* gp = (const bf16*)a0;
    const float* bias = (const float*)a1;
    #pragma unroll
    for (int m = 0; m < 4; ++m)
      #pragma unroll
      for (int n = 0; n < 4; ++n)
        #pragma unroll
        for (int reg = 0; reg < 4; ++reg) {
          int r = m0 + wm + m*16 + rq + reg;
          int c = n0 + wn + n*16 + cl;
          float l = acc[m][n][reg] + bias[c];
          op[(size_t)r*N + c] = (bf16)((float)gp[(size_t)r*N + c] * l);
        }
  } else if constexpr (EPI == 4) {
    float* op = (float*)o0 + (size_t)kb * M * N;
    #pragma unroll
    for (int m = 0; m < 4; ++m)
      #pragma unroll
      for (int n = 0; n < 4; ++n)
        #pragma unroll
        for (int reg = 0; reg < 4; ++reg) {
          int r = m0 + wm + m*16 + rq + reg;
          int c = n0 + wn + n*16 + cl;
          op[(size_t)r*N + c] = acc[m][n][reg];
        }
  }
}

// ---------------- fused attention (no-max softmax, fragment-layout inputs) -
// QF,KF,VF: fragment-ordered (see EPI 0). Block = 128 q-rows x 4 waves,
// kv loop over 64 tiles of 32; K/V tiles staged to LDS via coalesced
// global_load_lds (4KB contiguous each), shared by all 4 waves.
// AO: [B*S][1024] bf16
__global__ void __launch_bounds__(256) attn_kernel(
    const bf16* __restrict__ qf_g, const bf16* __restrict__ kf_g,
    const bf16* __restrict__ vf_g, bf16* __restrict__ ao_g) {
  __shared__ __align__(16) bf16 lds_k[2048];
  __shared__ __align__(16) bf16 lds_v[2048];
  const int tid  = threadIdx.x;
  const int lane = tid & 63;
  const int qw   = tid >> 6;      // wave's 32-row q group (0..3)
  const int hi   = lane >> 5;
  const int ql   = lane & 31;
  const int bh   = blockIdx.y;
  const int b_   = bh >> 4, h = bh & 15;
  const int q0   = blockIdx.x * 128 + qw * 32;
  const int qt   = blockIdx.x * 4 + qw;

  const bf16* qtile = qf_g + ((size_t)bh*64 + qt) * 2048;
  const bf16* kbase = kf_g + (size_t)bh * 64 * 2048;
  const bf16* vbase = vf_g + (size_t)bh * 64 * 2048;

  bf16x8 qf[4];
  #pragma unroll
  for (int ds = 0; ds < 4; ++ds)
    qf[ds] = *(const bf16x8*)&qtile[ds*512 + lane*8];

  f32x16 o0 = {}, o1 = {};
  float lrun = 0.f;
  const float SC = 0.18033688011112042f;   // 0.125 * log2(e)

  for (int t = 0; t < 64; ++t) {
    __syncthreads();
    gload16(kbase + (size_t)t*2048 + tid*8, &lds_k[tid*8]);
    gload16(vbase + (size_t)t*2048 + tid*8, &lds_v[tid*8]);
    __syncthreads();

    f32x16 st = {};
    __builtin_amdgcn_s_setprio(1);
    #pragma unroll
    for (int ds = 0; ds < 4; ++ds) {
      bf16x8 kf = *(const bf16x8*)&lds_k[ds*512 + lane*8];
      st = __builtin_amdgcn_mfma_f32_32x32x16_bf16(kf, qf[ds], st, 0, 0, 0);
    }
    __builtin_amdgcn_s_setprio(0);
    // st[reg] = S^T[k = (reg&3)+8*(reg>>2)+4*hi + t*32][q = ql]  (unscaled)
    float p[16];
    float psum = 0.f;
    #pragma unroll
    for (int r = 0; r < 16; ++r) { p[r] = exp2f(st[r] * SC); psum += p[r]; }
    psum += __shfl_xor(psum, 32);
    lrun += psum;

    uint32_t w[8], sw[8];
    #pragma unroll
    for (int i = 0; i < 8; ++i) w[i] = pkbf(p[2*i], p[2*i+1]);
    #pragma unroll
    for (int i = 0; i < 8; ++i) sw[i] = __shfl_xor(w[i], 32);

    __builtin_amdgcn_s_setprio(1);
    #pragma unroll
    for (int ks = 0; ks < 2; ++ks) {
      u32x4 pw;
      pw.x = hi ? sw[4*ks+2] : w[4*ks];
      pw.y = hi ? sw[4*ks+3] : w[4*ks+1];
      pw.z = hi ? w[4*ks+2]  : sw[4*ks];
      pw.w = hi ? w[4*ks+3]  : sw[4*ks+1];
      union { u32x4 u; bf16x8 b; } pu; pu.u = pw;
      bf16x8 v0 = *(const bf16x8*)&lds_v[(ks*2 + 0)*512 + lane*8];
      bf16x8 v1 = *(const bf16x8*)&lds_v[(ks*2 + 1)*512 + lane*8];
      o0 = __builtin_amdgcn_mfma_f32_32x32x16_bf16(v0, pu.b, o0, 0, 0, 0);
      o1 = __builtin_amdgcn_mfma_f32_32x32x16_bf16(v1, pu.b, o1, 0, 0, 0);
    }
    __builtin_amdgcn_s_setprio(0);
  }

  float inv = 1.f / lrun;
  bf16* aop = ao_g + ((size_t)(b_*SSEQ) + q0 + ql) * DIMN + h*HD;
  #pragma unroll
  for (int g = 0; g < 4; ++g) {
    int dbase = 8*g + 4*hi;
    bf16x4 w0 = {(bf16)(o0[4*g]*inv), (bf16)(o0[4*g+1]*inv),
                 (bf16)(o0[4*g+2]*inv), (bf16)(o0[4*g+3]*inv)};
    *(bf16x4*)&aop[dbase] = w0;
    bf16x4 w1 = {(bf16)(o1[4*g]*inv), (bf16)(o1[4*g+1]*inv),
                 (bf16)(o1[4*g+2]*inv), (bf16)(o1[4*g+3]*inv)};
    *(bf16x4*)&aop[32 + dbase] = w1;
  }
}

// ---------------------------------------------------------------------------
// Workspace layout (bytes), max footprint 126,353,408 (same as previous):
//   wt   [0,        8388608)   8MB  weight^T staging (reused per-gemm)
//   rope [8388608,  8912896)   0.5MB
//   xb   [8912896, 17301504)   8MB  x bf16; reused as AO after attn;
//                                   reused again as part of nothing (ffb covers)
//   qkv  [17301504,42467328)  24MB  QF/KF/VF fragment layouts
//   P1   [17301504,50855936)  32MB  out-proj split-2 partials (qkv dead)
//   g    [50855936,84410368)  32MB  gate output (P1 dead)
//   h1b  [84410368,92798976)   8MB  rmsnorm1 bf16 out
//   ffb  [8912896, 42467328)  32MB  swiglu out (ao/qkv dead)
//   P2   [42467328,109576192) 64MB  ff-out split-4 partials (g/h1b dead)
//   h1f  [109576192,126353408)16MB  rmsnorm1 f32 out (long-lived resid)
extern "C" void kernel_launch(void* const* d_in, const int* in_sizes, int n_in,
                              void* d_out, int out_size, void* d_ws, size_t ws_size,
                              hipStream_t stream) {
  const float* x      = (const float*)d_in[0];
  const float* w_qkv  = (const float*)d_in[1];
  const float* w_ao   = (const float*)d_in[2];
  const float* w_gate = (const float*)d_in[3];
  const float* b_gate = (const float*)d_in[4];
  const float* w_lin  = (const float*)d_in[5];
  const float* b_lin  = (const float*)d_in[6];
  const float* w_ffo  = (const float*)d_in[7];
  const float* scale1 = (const float*)d_in[8];
  const float* scale2 = (const float*)d_in[9];
  float* out = (float*)d_out;
  (void)ws_size; (void)in_sizes; (void)n_in; (void)out_size;

  uint8_t* ws = (uint8_t*)d_ws;
  bf16*  wt_ws   = (bf16*) (ws + 0);
  float* rope_ws = (float*)(ws + 8388608);
  bf16*  xb_ws   = (bf16*) (ws + 8912896);
  bf16*  ao_ws   = (bf16*) (ws + 8912896);    // reuse XB
  bf16*  q_ws    = (bf16*) (ws + 17301504);
  bf16*  k_ws    = (bf16*) (ws + 25690112);
  bf16*  v_ws    = (bf16*) (ws + 34078720);
  float* p1_ws   = (float*)(ws + 17301504);   // 32MB, reuse QKV region
  bf16*  g_ws    = (bf16*) (ws + 50855936);   // 32MB
  bf16*  h1b_ws  = (bf16*) (ws + 84410368);   // 8MB
  bf16*  ffb_ws  = (bf16*) (ws + 8912896);    // 32MB, reuse XB/AO + QKV head
  float* p2_ws   = (float*)(ws + 42467328);   // 64MB, reuse g/h1b + gap
  float* h1f_ws  = (float*)(ws + 109576192);  // 16MB

  // 1. rope table + x cast + w_qkv^T
  rope_table_kernel<<<256, 256, 0, stream>>>(rope_ws);
  cast_f32_bf16<<<4096, 256, 0, stream>>>(x, xb_ws, MROWS*DIMN/4);
  transpose_cast_f32_bf16<<<dim3(3*DIMN/32, DIMN/32), dim3(32,8), 0, stream>>>(w_qkv, wt_ws, DIMN, 3*DIMN);
  // 2. QKV gemm + rope epilogue -> fragment-layout QF/KF/VF
  gemm_bt<0><<<dim3(24, 32), 256, 0, stream>>>(xb_ws, wt_ws, MROWS, 3*DIMN, DIMN,
                                               q_ws, k_ws, v_ws, rope_ws, nullptr);
  // 3. attention (128 q-rows x 4 waves per block, LDS-staged K/V tiles)
  attn_kernel<<<dim3(16, 32), 256, 0, stream>>>(q_ws, k_ws, v_ws, ao_ws);
  // 4. out-proj, split-K=2 -> f32 partials (resid folded into rmsnorm)
  transpose_cast_f32_bf16<<<dim3(DIMN/32, DIMN/32), dim3(32,8), 0, stream>>>(w_ao, wt_ws, DIMN, DIMN);
  gemm_bt<4><<<dim3(8, 32, 2), 256, 0, stream>>>(ao_ws, wt_ws, MROWS, DIMN, DIMN,
                                                 p1_ws, nullptr, nullptr, nullptr, nullptr);
  // 5. rmsnorm1 over (p0+p1+x) -> f32 + bf16
  rmsnorm_sum_kernel<2><<<MROWS, 256, 0, stream>>>(p1_ws, x, scale1, h1f_ws, h1b_ws);
  // 6. gate gemm -> sigmoid bf16
  transpose_cast_f32_bf16<<<dim3(FFN/32, DIMN/32), dim3(32,8), 0, stream>>>(w_gate, wt_ws, DIMN, FFN);
  gemm_bt<2><<<dim3(32, 32), 256, 0, stream>>>(h1b_ws, wt_ws, MROWS, FFN, DIMN,
                                               g_ws, nullptr, nullptr, b_gate, nullptr);
  // 7. lin gemm -> * gate -> bf16
  transpose_cast_f32_bf16<<<dim3(FFN/32, DIMN/32), dim3(32,8), 0, stream>>>(w_lin, wt_ws, DIMN, FFN);
  gemm_bt<3><<<dim3(32, 32), 256, 0, stream>>>(h1b_ws, wt_ws, MROWS, FFN, DIMN,
                                               ffb_ws, nullptr, nullptr, g_ws, b_lin);
  // 8. ff-out gemm, split-K=4 -> f32 partials
  transpose_cast_f32_bf16<<<dim3(DIMN/32, FFN/32), dim3(32,8), 0, stream>>>(w_ffo, wt_ws, FFN, DIMN);
  gemm_bt<4><<<dim3(8, 32, 4), 256, 0, stream>>>(ffb_ws, wt_ws, MROWS, DIMN, FFN,
                                                 p2_ws, nullptr, nullptr, nullptr, nullptr);
  // 9. rmsnorm2 over (p0+p1+p2+p3+h1f) -> output (f32)
  rmsnorm_sum_kernel<4><<<MROWS, 256, 0, stream>>>(p2_ws, h1f_ws, scale2, out, nullptr);
}

// Round 2
// 366.234 us; speedup vs baseline: 1.1191x; 1.0566x over previous
//
#include <hip/hip_runtime.h>
#include <stdint.h>

#define DIMN 1024
#define NH 16
#define HD 64
#define FFN 4096
#define BBATCH 2
#define SSEQ 2048
#define MROWS (BBATCH*SSEQ)   // 4096

typedef __bf16 bf16;
typedef __bf16 bf16x8 __attribute__((ext_vector_type(8)));
typedef __bf16 bf16x4 __attribute__((ext_vector_type(4)));
typedef float f32x4 __attribute__((ext_vector_type(4)));
typedef float f32x16 __attribute__((ext_vector_type(16)));
typedef uint32_t u32x4 __attribute__((ext_vector_type(4)));

#define AS1 __attribute__((address_space(1)))
#define AS3 __attribute__((address_space(3)))

__device__ __forceinline__ void gload16(const bf16* g, bf16* l) {
  __builtin_amdgcn_global_load_lds((AS1 const void*)g, (AS3 void*)l, 16, 0, 0);
}

__device__ __forceinline__ uint32_t pkbf(float a, float b) {
  union { bf16 h[2]; uint32_t u; } x;
  x.h[0] = (bf16)a; x.h[1] = (bf16)b;
  return x.u;
}

// ---------------- rope table: tab[s*64 + d] = cos, tab[s*64+32+d] = sin ----
__global__ void rope_table_kernel(float* __restrict__ tab) {
  int i = blockIdx.x * blockDim.x + threadIdx.x;   // 0..65535
  int s = i >> 5, d = i & 31;
  float invf = exp2f(-(float)d * 0.4152410118609203f);
  float fr = (float)s * invf;
  tab[s*64 + d]      = cosf(fr);
  tab[s*64 + 32 + d] = sinf(fr);
}

// ---------------- f32 -> bf16 cast (vector x4) -----------------------------
__global__ void cast_f32_bf16(const float* __restrict__ in, bf16* __restrict__ out, int n4) {
  int i = blockIdx.x * blockDim.x + threadIdx.x;
  if (i < n4) {
    f32x4 v = ((const f32x4*)in)[i];
    bf16x4 o = {(bf16)v.x, (bf16)v.y, (bf16)v.z, (bf16)v.w};
    ((bf16x4*)out)[i] = o;
  }
}

// ---------------- transpose + cast: f32 [R][C] -> bf16 [C][R] --------------
__global__ __launch_bounds__(256) void transpose_cast_f32_bf16(
    const float* __restrict__ in, bf16* __restrict__ out, int R, int C) {
  __shared__ float t[32][33];
  int bx = blockIdx.x, by = blockIdx.y;
  int x = threadIdx.x, y = threadIdx.y;     // (32, 8)
  #pragma unroll
  for (int j = 0; j < 4; ++j) {
    int r = by*32 + y*4 + j;
    t[y*4+j][x] = in[(size_t)r*C + bx*32 + x];
  }
  __syncthreads();
  #pragma unroll
  for (int j = 0; j < 4; ++j) {
    int c = bx*32 + y*4 + j;
    out[(size_t)c*R + by*32 + x] = (bf16)t[x][y*4+j];
  }
}

// ---------------- RMSNorm over (sum of NP partials + resid) ----------------
// parts: NP contiguous f32 [MROWS][DIMN] planes (stride MROWS*DIMN floats)
template<int NP>
__global__ __launch_bounds__(256) void rmsnorm_sum_kernel(
    const float* __restrict__ parts, const float* __restrict__ resid,
    const float* __restrict__ sc,
    float* __restrict__ outf, bf16* __restrict__ outb) {
  int row = blockIdx.x;
  int tid = threadIdx.x;
  size_t off = (size_t)row * DIMN;
  f32x4 v = ((const f32x4*)(resid + off))[tid];
  #pragma unroll
  for (int p = 0; p < NP; ++p) {
    f32x4 a = ((const f32x4*)(parts + (size_t)p * MROWS * DIMN + off))[tid];
    v.x += a.x; v.y += a.y; v.z += a.z; v.w += a.w;
  }
  float ss = v.x*v.x + v.y*v.y + v.z*v.z + v.w*v.w;
  #pragma unroll
  for (int m = 1; m < 64; m <<= 1) ss += __shfl_xor(ss, m);
  __shared__ float red[4];
  if ((tid & 63) == 0) red[tid >> 6] = ss;
  __syncthreads();
  float tot = red[0] + red[1] + red[2] + red[3];
  float inv = 1.f / (sqrtf(tot) * 0.03125f + 1e-8f);
  f32x4 s4 = ((const f32x4*)sc)[tid];
  f32x4 o = {v.x*s4.x*inv, v.y*s4.y*inv, v.z*s4.z*inv, v.w*s4.w*inv};
  if (outf) ((f32x4*)(outf + off))[tid] = o;
  if (outb) {
    bf16x4 ob = {(bf16)o.x, (bf16)o.y, (bf16)o.z, (bf16)o.w};
    ((bf16x4*)(outb + off))[tid] = ob;
  }
}

// ---------------- GEMM: C[M][N] = A[M][K] * B^T[N][K]  (m97 structure) -----
// Split-K via gridDim.z: block z computes K-chunk [z*KC, (z+1)*KC).
// EPI 0: QKV+rope -> fragment-layout Q/K/V for attention. Q additionally
//        pre-scaled by 0.125*log2(e) so attn's softmax can exp2 directly.
// EPI 1: f32 out = acc + resid   (o0=f32 out, a0=f32 resid, both [M][N])
// EPI 2: bf16 out = sigmoid(acc + bias[col])   (o0=bf16 out, a0=f32 bias)
// EPI 3: bf16 out = gate[r][c] * (acc + bias[col]) (o0=bf16, a0=bf16 gate, a1=f32 bias)
// EPI 4: f32 partial: o0[z*M*N + r*N + c] = acc   (split-K, no resid)
template<int EPI>
__global__ void __launch_bounds__(256) gemm_bt(
    const bf16* __restrict__ A, const bf16* __restrict__ B,
    int M, int N, int K,
    void* __restrict__ o0, void* __restrict__ o1, void* __restrict__ o2,
    const void* __restrict__ a0, const void* __restrict__ a1) {
  __shared__ __align__(16) bf16 sh_a[128*32];
  __shared__ __align__(16) bf16 sh_b[128*32];
  const int tid  = threadIdx.x;
  const int lane = tid & 63;
  const int wid  = tid >> 6;

  // XCD-aware swizzle (all our grids have nwg % 8 == 0 -> bijective)
  int gx  = gridDim.x;
  int bid = blockIdx.y * gx + blockIdx.x;
  int nwg = gx * gridDim.y;
  int cpx = nwg >> 3;
  int swz = (bid & 7) * cpx + (bid >> 3);
  int bxi = swz % gx, byi = swz / gx;

  const int m0 = byi * 128, n0 = bxi * 128;
  const int wm = (wid >> 1) * 64, wn = (wid & 1) * 64;

  // split-K chunk
  const int kb = blockIdx.z;
  const int KC = K / (int)gridDim.z;

  f32x4 acc[4][4] = {};

  const bf16* a_base = A + (size_t)m0 * K + (size_t)kb * KC;
  const bf16* b_base = B + (size_t)n0 * K + (size_t)kb * KC;

  for (int k0 = 0; k0 < KC; k0 += 32) {
    __syncthreads();
    #pragma unroll
    for (int i = 0; i < 2; ++i) {
      int idx = i*256 + tid;
      gload16(a_base + (size_t)(idx >> 2)*K + k0 + (idx & 3)*8, &sh_a[idx*8]);
    }
    #pragma unroll
    for (int i = 0; i < 2; ++i) {
      int idx = i*256 + tid;
      gload16(b_base + (size_t)(idx >> 2)*K + k0 + (idx & 3)*8, &sh_b[idx*8]);
    }
    __syncthreads();
    bf16x8 af[4], bfr[4];
    #pragma unroll
    for (int m = 0; m < 4; ++m)
      af[m] = *(const bf16x8*)&sh_a[(wm + m*16 + (lane & 15))*32 + (lane >> 4)*8];
    #pragma unroll
    for (int n = 0; n < 4; ++n)
      bfr[n] = *(const bf16x8*)&sh_b[(wn + n*16 + (lane & 15))*32 + (lane >> 4)*8];
    #pragma unroll
    for (int m = 0; m < 4; ++m)
      #pragma unroll
      for (int n = 0; n < 4; ++n)
        acc[m][n] = __builtin_amdgcn_mfma_f32_16x16x32_bf16(af[m], bfr[n], acc[m][n], 0, 0, 0);
  }

  const int rq = (lane >> 4) * 4;
  const int cl = lane & 15;

  if constexpr (EPI == 0) {
    bf16* q_p = (bf16*)o0; bf16* k_p = (bf16*)o1; bf16* v_p = (bf16*)o2;
    const float* rope = (const float*)a0;
    int sec = (n0 + wn) >> 10;             // 0=q, 1=k, 2=v
    int h   = ((n0 + wn) & 1023) >> 6;
    const float qsc = (sec == 0) ? 0.18033688011112042f : 1.0f;  // 0.125*log2(e)
    #pragma unroll
    for (int m = 0; m < 4; ++m) {
      #pragma unroll
      for (int reg = 0; reg < 4; ++reg) {
        int r  = m0 + wm + m*16 + rq + reg;
        int b_ = r >> 11, s_ = r & 2047;
        int tile = s_ >> 5;
        size_t tb = ((size_t)(b_*NH + h) * 64 + tile) * 2048;  // 4KB tile base
        if (sec == 2) {
          int kvl = s_ & 31;
          int ks = kvl >> 4, hiv = (kvl >> 3) & 1, jv = kvl & 7;
          #pragma unroll
          for (int n = 0; n < 4; ++n) {
            int half = n >> 1;
            int qlv  = (n & 1) * 16 + cl;
            v_p[tb + (size_t)(ks*2 + half)*512 + (hiv*32 + qlv)*8 + jv] =
                (bf16)acc[m][n][reg];
          }
        } else {
          int qlt = s_ & 31;
          bf16* dst = (sec == 0 ? q_p : k_p);
          int lo = ((cl >> 3) * 32 + qlt) * 8 + (cl & 7);
          #pragma unroll
          for (int n = 0; n < 2; ++n) {
            int d1 = n*16 + cl;
            float c1 = rope[s_*64 + d1];
            float s1 = rope[s_*64 + 32 + d1];
            float x1 = acc[m][n][reg], x2 = acc[m][n+2][reg];
            dst[tb + (size_t)n*512 + lo]       = (bf16)((x1*c1 - x2*s1) * qsc);
            dst[tb + (size_t)(n+2)*512 + lo]   = (bf16)((x1*s1 + x2*c1) * qsc);
          }
        }
      }
    }
  } else if constexpr (EPI == 1) {
    float* op = (float*)o0;
    const float* rp = (const float*)a0;
    #pragma unroll
    for (int m = 0; m < 4; ++m)
      #pragma unroll
      for (int n = 0; n < 4; ++n)
        #pragma unroll
        for (int reg = 0; reg < 4; ++reg) {
          int r = m0 + wm + m*16 + rq + reg;
          int c = n0 + wn + n*16 + cl;
          op[(size_t)r*N + c] = acc[m][n][reg] + rp[(size_t)r*N + c];
        }
  } else if constexpr (EPI == 2) {
    bf16* op = (bf16*)o0;
    const float* bias = (const float*)a0;
    #pragma unroll
    for (int m = 0; m < 4; ++m)
      #pragma unroll
      for (int n = 0; n < 4; ++n)
        #pragma unroll
        for (int reg = 0; reg < 4; ++reg) {
          int r = m0 + wm + m*16 + rq + reg;
          int c = n0 + wn + n*16 + cl;
          float g = acc[m][n][reg] + bias[c];
          op[(size_t)r*N + c] = (bf16)(1.f / (1.f + __expf(-g)));
        }
  } else if constexpr (EPI == 3) {
    bf16* op = (bf16*)o0;
    const bf16* gp = (const bf16*)a0;
    const float* bias = (const float*)a1;
    #pragma unroll
    for (int m = 0; m < 4; ++m)
      #pragma unroll
      for (int n = 0; n < 4; ++n)
        #pragma unroll
        for (int reg = 0; reg < 4; ++reg) {
          int r = m0 + wm + m*16 + rq + reg;
          int c = n0 + wn + n*16 + cl;
          float l = acc[m][n][reg] + bias[c];
          op[(size_t)r*N + c] = (bf16)((float)gp[(size_t)r*N + c] * l);
        }
  } else if constexpr (EPI == 4) {
    float* op = (float*)o0 + (size_t)kb * M * N;
    #pragma unroll
    for (int m = 0; m < 4; ++m)
      #pragma unroll
      for (int n = 0; n < 4; ++n)
        #pragma unroll
        for (int reg = 0; reg < 4; ++reg) {
          int r = m0 + wm + m*16 + rq + reg;
          int c = n0 + wn + n*16 + cl;
          op[(size_t)r*N + c] = acc[m][n][reg];
        }
  }
}

// ---------------- fused attention (no-max softmax, fragment-layout inputs) -
// QF,KF,VF: fragment-ordered (see EPI 0; Q pre-scaled by 0.125*log2e).
// Block = 128 q-rows x 4 waves, kv loop over 64 tiles of 32.
// Double-buffered LDS staging: raw s_barrier + counted vmcnt(2) so next
// tile's global_load_lds stays in flight across the barrier (T3/T4).
// Softmax: raw v_exp_f32, half-wave transpose via 4x v_permlane32_swap_b32,
// cross-half l-sum deferred to after the loop.
// AO: [B*S][1024] bf16
__global__ void __launch_bounds__(256) attn_kernel(
    const bf16* __restrict__ qf_g, const bf16* __restrict__ kf_g,
    const bf16* __restrict__ vf_g, bf16* __restrict__ ao_g) {
  __shared__ __align__(16) bf16 lds_k[2*2048];
  __shared__ __align__(16) bf16 lds_v[2*2048];
  const int tid  = threadIdx.x;
  const int lane = tid & 63;
  const int qw   = tid >> 6;      // wave's 32-row q group (0..3)
  const int hi   = lane >> 5;
  const int ql   = lane & 31;
  const int bh   = blockIdx.y;
  const int b_   = bh >> 4, h = bh & 15;
  const int q0   = blockIdx.x * 128 + qw * 32;
  const int qt   = blockIdx.x * 4 + qw;

  const bf16* qtile = qf_g + ((size_t)bh*64 + qt) * 2048;
  const bf16* kbase = kf_g + (size_t)bh * 64 * 2048;
  const bf16* vbase = vf_g + (size_t)bh * 64 * 2048;

  bf16x8 qf[4];
  #pragma unroll
  for (int ds = 0; ds < 4; ++ds)
    qf[ds] = *(const bf16x8*)&qtile[ds*512 + lane*8];

  f32x16 o0 = {}, o1 = {};
  float lrun = 0.f;

  // prologue: stage tile 0 into buffer 0
  gload16(kbase + tid*8, &lds_k[tid*8]);
  gload16(vbase + tid*8, &lds_v[tid*8]);

  for (int t = 0; t < 64; ++t) {
    const int cur = (t & 1) * 2048;
    if (t < 63) {
      const int nxt = 2048 - cur;
      gload16(kbase + (size_t)(t+1)*2048 + tid*8, &lds_k[nxt + tid*8]);
      gload16(vbase + (size_t)(t+1)*2048 + tid*8, &lds_v[nxt + tid*8]);
      asm volatile("s_waitcnt vmcnt(2)" ::: "memory");   // drain tile t only
    } else {
      asm volatile("s_waitcnt vmcnt(0)" ::: "memory");
    }
    __builtin_amdgcn_sched_barrier(0);
    __builtin_amdgcn_s_barrier();          // tile t visible to all waves
    __builtin_amdgcn_sched_barrier(0);

    f32x16 st = {};
    __builtin_amdgcn_s_setprio(1);
    #pragma unroll
    for (int ds = 0; ds < 4; ++ds) {
      bf16x8 kf = *(const bf16x8*)&lds_k[cur + ds*512 + lane*8];
      st = __builtin_amdgcn_mfma_f32_32x32x16_bf16(kf, qf[ds], st, 0, 0, 0);
    }
    __builtin_amdgcn_s_setprio(0);
    // st[reg] = (S*0.125*log2e)^T[k = (reg&3)+8*(reg>>2)+4*hi + t*32][q = ql]
    float p[16];
    float psum = 0.f;
    #pragma unroll
    for (int r = 0; r < 16; ++r) { p[r] = __builtin_amdgcn_exp2f(st[r]); psum += p[r]; }
    lrun += psum;                           // own half only; cross-half after loop

    uint32_t w0 = pkbf(p[0],p[1]),   w1 = pkbf(p[2],p[3]);
    uint32_t w2 = pkbf(p[4],p[5]),   w3 = pkbf(p[6],p[7]);
    uint32_t w4 = pkbf(p[8],p[9]),   w5 = pkbf(p[10],p[11]);
    uint32_t w6 = pkbf(p[12],p[13]), w7 = pkbf(p[14],p[15]);
    // half-wave transpose: a' = (aL,bL), b' = (aH,bH)
    asm("v_permlane32_swap_b32 %0, %1" : "+v"(w0), "+v"(w2));
    asm("v_permlane32_swap_b32 %0, %1" : "+v"(w1), "+v"(w3));
    asm("v_permlane32_swap_b32 %0, %1" : "+v"(w4), "+v"(w6));
    asm("v_permlane32_swap_b32 %0, %1" : "+v"(w5), "+v"(w7));

    __builtin_amdgcn_s_setprio(1);
    {
      union { u32x4 u; bf16x8 b; } pu;
      u32x4 pwa = {w0, w1, w2, w3};
      pu.u = pwa;
      bf16x8 v0 = *(const bf16x8*)&lds_v[cur + 0*512 + lane*8];
      bf16x8 v1 = *(const bf16x8*)&lds_v[cur + 1*512 + lane*8];
      o0 = __builtin_amdgcn_mfma_f32_32x32x16_bf16(v0, pu.b, o0, 0, 0, 0);
      o1 = __builtin_amdgcn_mfma_f32_32x32x16_bf16(v1, pu.b, o1, 0, 0, 0);
      u32x4 pwb = {w4, w5, w6, w7};
      pu.u = pwb;
      bf16x8 v2 = *(const bf16x8*)&lds_v[cur + 2*512 + lane*8];
      bf16x8 v3 = *(const bf16x8*)&lds_v[cur + 3*512 + lane*8];
      o0 = __builtin_amdgcn_mfma_f32_32x32x16_bf16(v2, pu.b, o0, 0, 0, 0);
      o1 = __builtin_amdgcn_mfma_f32_32x32x16_bf16(v3, pu.b, o1, 0, 0, 0);
    }
    __builtin_amdgcn_s_setprio(0);

    __builtin_amdgcn_sched_barrier(0);
    __builtin_amdgcn_s_barrier();          // all waves done reading buf cur
    __builtin_amdgcn_sched_barrier(0);
  }

  lrun += __shfl_xor(lrun, 32);
  float inv = 1.f / lrun;
  bf16* aop = ao_g + ((size_t)(b_*SSEQ) + q0 + ql) * DIMN + h*HD;
  #pragma unroll
  for (int g = 0; g < 4; ++g) {
    int dbase = 8*g + 4*hi;
    bf16x4 w0 = {(bf16)(o0[4*g]*inv), (bf16)(o0[4*g+1]*inv),
                 (bf16)(o0[4*g+2]*inv), (bf16)(o0[4*g+3]*inv)};
    *(bf16x4*)&aop[dbase] = w0;
    bf16x4 w1 = {(bf16)(o1[4*g]*inv), (bf16)(o1[4*g+1]*inv),
                 (bf16)(o1[4*g+2]*inv), (bf16)(o1[4*g+3]*inv)};
    *(bf16x4*)&aop[32 + dbase] = w1;
  }
}

// ---------------------------------------------------------------------------
// Workspace layout (bytes), max footprint 126,353,408:
//   wt   [0,        8388608)   8MB  weight^T staging (reused per-gemm)
//   rope [8388608,  8912896)   0.5MB
//   xb   [8912896, 17301504)   8MB  x bf16; reused as AO after attn
//   qkv  [17301504,42467328)  24MB  QF/KF/VF fragment layouts
//   P1   [17301504,50855936)  32MB  out-proj split-2 partials (qkv dead)
//   g    [50855936,84410368)  32MB  gate output (P1 dead)
//   h1b  [84410368,92798976)   8MB  rmsnorm1 bf16 out
//   ffb  [8912896, 42467328)  32MB  swiglu out (ao/qkv dead)
//   P2   [42467328,109576192) 64MB  ff-out split-4 partials (g/h1b dead)
//   h1f  [109576192,126353408)16MB  rmsnorm1 f32 out (long-lived resid)
extern "C" void kernel_launch(void* const* d_in, const int* in_sizes, int n_in,
                              void* d_out, int out_size, void* d_ws, size_t ws_size,
                              hipStream_t stream) {
  const float* x      = (const float*)d_in[0];
  const float* w_qkv  = (const float*)d_in[1];
  const float* w_ao   = (const float*)d_in[2];
  const float* w_gate = (const float*)d_in[3];
  const float* b_gate = (const float*)d_in[4];
  const float* w_lin  = (const float*)d_in[5];
  const float* b_lin  = (const float*)d_in[6];
  const float* w_ffo  = (const float*)d_in[7];
  const float* scale1 = (const float*)d_in[8];
  const float* scale2 = (const float*)d_in[9];
  float* out = (float*)d_out;
  (void)ws_size; (void)in_sizes; (void)n_in; (void)out_size;

  uint8_t* ws = (uint8_t*)d_ws;
  bf16*  wt_ws   = (bf16*) (ws + 0);
  float* rope_ws = (float*)(ws + 8388608);
  bf16*  xb_ws   = (bf16*) (ws + 8912896);
  bf16*  ao_ws   = (bf16*) (ws + 8912896);    // reuse XB
  bf16*  q_ws    = (bf16*) (ws + 17301504);
  bf16*  k_ws    = (bf16*) (ws + 25690112);
  bf16*  v_ws    = (bf16*) (ws + 34078720);
  float* p1_ws   = (float*)(ws + 17301504);   // 32MB, reuse QKV region
  bf16*  g_ws    = (bf16*) (ws + 50855936);   // 32MB
  bf16*  h1b_ws  = (bf16*) (ws + 84410368);   // 8MB
  bf16*  ffb_ws  = (bf16*) (ws + 8912896);    // 32MB, reuse XB/AO + QKV head
  float* p2_ws   = (float*)(ws + 42467328);   // 64MB, reuse g/h1b + gap
  float* h1f_ws  = (float*)(ws + 109576192);  // 16MB

  // 1. rope table + x cast + w_qkv^T
  rope_table_kernel<<<256, 256, 0, stream>>>(rope_ws);
  cast_f32_bf16<<<4096, 256, 0, stream>>>(x, xb_ws, MROWS*DIMN/4);
  transpose_cast_f32_bf16<<<dim3(3*DIMN/32, DIMN/32), dim3(32,8), 0, stream>>>(w_qkv, wt_ws, DIMN, 3*DIMN);
  // 2. QKV gemm + rope epilogue -> fragment-layout QF/KF/VF (Q pre-scaled)
  gemm_bt<0><<<dim3(24, 32), 256, 0, stream>>>(xb_ws, wt_ws, MROWS, 3*DIMN, DIMN,
                                               q_ws, k_ws, v_ws, rope_ws, nullptr);
  // 3. attention (double-buffered KV staging, counted vmcnt)
  attn_kernel<<<dim3(16, 32), 256, 0, stream>>>(q_ws, k_ws, v_ws, ao_ws);
  // 4. out-proj, split-K=2 -> f32 partials (resid folded into rmsnorm)
  transpose_cast_f32_bf16<<<dim3(DIMN/32, DIMN/32), dim3(32,8), 0, stream>>>(w_ao, wt_ws, DIMN, DIMN);
  gemm_bt<4><<<dim3(8, 32, 2), 256, 0, stream>>>(ao_ws, wt_ws, MROWS, DIMN, DIMN,
                                                 p1_ws, nullptr, nullptr, nullptr, nullptr);
  // 5. rmsnorm1 over (p0+p1+x) -> f32 + bf16
  rmsnorm_sum_kernel<2><<<MROWS, 256, 0, stream>>>(p1_ws, x, scale1, h1f_ws, h1b_ws);
  // 6. gate gemm -> sigmoid bf16
  transpose_cast_f32_bf16<<<dim3(FFN/32, DIMN/32), dim3(32,8), 0, stream>>>(w_gate, wt_ws, DIMN, FFN);
  gemm_bt<2><<<dim3(32, 32), 256, 0, stream>>>(h1b_ws, wt_ws, MROWS, FFN, DIMN,
                                               g_ws, nullptr, nullptr, b_gate, nullptr);
  // 7. lin gemm -> * gate -> bf16
  transpose_cast_f32_bf16<<<dim3(FFN/32, DIMN/32), dim3(32,8), 0, stream>>>(w_lin, wt_ws, DIMN, FFN);
  gemm_bt<3><<<dim3(32, 32), 256, 0, stream>>>(h1b_ws, wt_ws, MROWS, FFN, DIMN,
                                               ffb_ws, nullptr, nullptr, g_ws, b_lin);
  // 8. ff-out gemm, split-K=4 -> f32 partials
  transpose_cast_f32_bf16<<<dim3(DIMN/32, FFN/32), dim3(32,8), 0, stream>>>(w_ffo, wt_ws, FFN, DIMN);
  gemm_bt<4><<<dim3(8, 32, 4), 256, 0, stream>>>(ffb_ws, wt_ws, MROWS, DIMN, FFN,
                                                 p2_ws, nullptr, nullptr, nullptr, nullptr);
  // 9. rmsnorm2 over (p0+p1+p2+p3+h1f) -> output (f32)
  rmsnorm_sum_kernel<4><<<MROWS, 256, 0, stream>>>(p2_ws, h1f_ws, scale2, out, nullptr);
}

// Round 3
// 311.630 us; speedup vs baseline: 1.3152x; 1.1752x over previous
//
#include <hip/hip_runtime.h>
#include <stdint.h>

#define DIMN 1024
#define NH 16
#define HD 64
#define FFN 4096
#define BBATCH 2
#define SSEQ 2048
#define MROWS (BBATCH*SSEQ)   // 4096

typedef __bf16 bf16;
typedef __bf16 bf16x8 __attribute__((ext_vector_type(8)));
typedef __bf16 bf16x4 __attribute__((ext_vector_type(4)));
typedef float f32x4 __attribute__((ext_vector_type(4)));
typedef float f32x16 __attribute__((ext_vector_type(16)));
typedef uint32_t u32x4 __attribute__((ext_vector_type(4)));

#define AS1 __attribute__((address_space(1)))
#define AS3 __attribute__((address_space(3)))

__device__ __forceinline__ void gload16(const bf16* g, bf16* l) {
  __builtin_amdgcn_global_load_lds((AS1 const void*)g, (AS3 void*)l, 16, 0, 0);
}

__device__ __forceinline__ uint32_t pkbf(float a, float b) {
  union { bf16 h[2]; uint32_t u; } x;
  x.h[0] = (bf16)a; x.h[1] = (bf16)b;
  return x.u;
}

// ---------------- rope table: tab[s*64 + d] = cos, tab[s*64+32+d] = sin ----
__global__ void rope_table_kernel(float* __restrict__ tab) {
  int i = blockIdx.x * blockDim.x + threadIdx.x;   // 0..65535
  int s = i >> 5, d = i & 31;
  float invf = exp2f(-(float)d * 0.4152410118609203f);
  float fr = (float)s * invf;
  tab[s*64 + d]      = cosf(fr);
  tab[s*64 + 32 + d] = sinf(fr);
}

// ---------------- f32 -> bf16 cast (vector x4) -----------------------------
__global__ void cast_f32_bf16(const float* __restrict__ in, bf16* __restrict__ out, int n4) {
  int i = blockIdx.x * blockDim.x + threadIdx.x;
  if (i < n4) {
    f32x4 v = ((const f32x4*)in)[i];
    bf16x4 o = {(bf16)v.x, (bf16)v.y, (bf16)v.z, (bf16)v.w};
    ((bf16x4*)out)[i] = o;
  }
}

// ---------------- transpose + cast: f32 [R][C] -> bf16 [C][R] --------------
__global__ __launch_bounds__(256) void transpose_cast_f32_bf16(
    const float* __restrict__ in, bf16* __restrict__ out, int R, int C) {
  __shared__ float t[32][33];
  int bx = blockIdx.x, by = blockIdx.y;
  int x = threadIdx.x, y = threadIdx.y;     // (32, 8)
  #pragma unroll
  for (int j = 0; j < 4; ++j) {
    int r = by*32 + y*4 + j;
    t[y*4+j][x] = in[(size_t)r*C + bx*32 + x];
  }
  __syncthreads();
  #pragma unroll
  for (int j = 0; j < 4; ++j) {
    int c = bx*32 + y*4 + j;
    out[(size_t)c*R + by*32 + x] = (bf16)t[x][y*4+j];
  }
}

// ---------------- RMSNorm over (sum of NP partials + resid) ----------------
// parts: NP contiguous f32 [MROWS][DIMN] planes (stride MROWS*DIMN floats)
template<int NP>
__global__ __launch_bounds__(256) void rmsnorm_sum_kernel(
    const float* __restrict__ parts, const float* __restrict__ resid,
    const float* __restrict__ sc,
    float* __restrict__ outf, bf16* __restrict__ outb) {
  int row = blockIdx.x;
  int tid = threadIdx.x;
  size_t off = (size_t)row * DIMN;
  f32x4 v = ((const f32x4*)(resid + off))[tid];
  #pragma unroll
  for (int p = 0; p < NP; ++p) {
    f32x4 a = ((const f32x4*)(parts + (size_t)p * MROWS * DIMN + off))[tid];
    v.x += a.x; v.y += a.y; v.z += a.z; v.w += a.w;
  }
  float ss = v.x*v.x + v.y*v.y + v.z*v.z + v.w*v.w;
  #pragma unroll
  for (int m = 1; m < 64; m <<= 1) ss += __shfl_xor(ss, m);
  __shared__ float red[4];
  if ((tid & 63) == 0) red[tid >> 6] = ss;
  __syncthreads();
  float tot = red[0] + red[1] + red[2] + red[3];
  float inv = 1.f / (sqrtf(tot) * 0.03125f + 1e-8f);
  f32x4 s4 = ((const f32x4*)sc)[tid];
  f32x4 o = {v.x*s4.x*inv, v.y*s4.y*inv, v.z*s4.z*inv, v.w*s4.w*inv};
  if (outf) ((f32x4*)(outf + off))[tid] = o;
  if (outb) {
    bf16x4 ob = {(bf16)o.x, (bf16)o.y, (bf16)o.z, (bf16)o.w};
    ((bf16x4*)(outb + off))[tid] = ob;
  }
}

// ---------------- GEMM: C[M][N] = A[M][K] * B^T[N][K] ----------------------
// Double-buffered LDS pipeline (T3/T4): stage tile t+1 before computing
// tile t; counted s_waitcnt vmcnt(N) so prefetch loads stay in flight
// across the barrier. Split-K via gridDim.z.
// EPI 0: QKV+rope -> fragment-layout Q/K/V (Q pre-scaled by 0.125*log2e)
// EPI 1: f32 out = acc + resid
// EPI 2: bf16 out = sigmoid(acc + bias[col])
// EPI 3: bf16 out = gate[r][c] * (acc + bias[col])
// EPI 4: f32 partial: o0[z*M*N + r*N + c] = acc   (split-K)
// EPI 5: fused FFN1: B=w_gate^T, o1=w_lin^T (2nd B), a0=b_gate, a1=b_lin;
//        out bf16 = sigmoid(accg + bg[c]) * (accl + bl[c])
template<int EPI>
__global__ void __launch_bounds__(256, 2) gemm_bt(
    const bf16* __restrict__ A, const bf16* __restrict__ B,
    int M, int N, int K,
    void* __restrict__ o0, void* __restrict__ o1, void* __restrict__ o2,
    const void* __restrict__ a0, const void* __restrict__ a1) {
  constexpr bool FUSED = (EPI == 5);
  __shared__ __align__(16) bf16 sh_a[2*4096];
  __shared__ __align__(16) bf16 sh_b[2*4096];
  __shared__ __align__(16) bf16 sh_c[FUSED ? 2*4096 : 4];
  const int tid  = threadIdx.x;
  const int lane = tid & 63;
  const int wid  = tid >> 6;

  // XCD-aware swizzle (all our grids have nwg % 8 == 0 -> bijective)
  int gx  = gridDim.x;
  int bid = blockIdx.y * gx + blockIdx.x;
  int nwg = gx * gridDim.y;
  int cpx = nwg >> 3;
  int swz = (bid & 7) * cpx + (bid >> 3);
  int bxi = swz % gx, byi = swz / gx;

  const int m0 = byi * 128, n0 = bxi * 128;
  const int wm = (wid >> 1) * 64, wn = (wid & 1) * 64;

  // split-K chunk
  const int kb = blockIdx.z;
  const int KC = K / (int)gridDim.z;

  f32x4 acc[4][4] = {};
  f32x4 acc2[FUSED ? 4 : 1][FUSED ? 4 : 1] = {};

  const bf16* a_base = A + (size_t)m0 * K + (size_t)kb * KC;
  const bf16* b_base = B + (size_t)n0 * K + (size_t)kb * KC;
  const bf16* c_base = nullptr;
  if constexpr (FUSED) c_base = (const bf16*)o1 + (size_t)n0 * K;

  auto stage = [&](int kt, int buf) {
    const int lb = buf * 4096;
    #pragma unroll
    for (int i = 0; i < 2; ++i) {
      int idx = i*256 + tid;
      size_t go = (size_t)(idx >> 2)*K + (size_t)kt*32 + (idx & 3)*8;
      gload16(a_base + go, &sh_a[lb + idx*8]);
    }
    #pragma unroll
    for (int i = 0; i < 2; ++i) {
      int idx = i*256 + tid;
      size_t go = (size_t)(idx >> 2)*K + (size_t)kt*32 + (idx & 3)*8;
      gload16(b_base + go, &sh_b[lb + idx*8]);
    }
    if constexpr (FUSED) {
      #pragma unroll
      for (int i = 0; i < 2; ++i) {
        int idx = i*256 + tid;
        size_t go = (size_t)(idx >> 2)*K + (size_t)kt*32 + (idx & 3)*8;
        gload16(c_base + go, &sh_c[lb + idx*8]);
      }
    }
  };

  const int nsteps = KC >> 5;
  stage(0, 0);
  for (int t = 0; t < nsteps; ++t) {
    const int cb = t & 1;
    if (t + 1 < nsteps) {
      stage(t+1, cb ^ 1);
      if constexpr (FUSED) asm volatile("s_waitcnt vmcnt(6)" ::: "memory");
      else                 asm volatile("s_waitcnt vmcnt(4)" ::: "memory");
    } else {
      asm volatile("s_waitcnt vmcnt(0)" ::: "memory");
    }
    __builtin_amdgcn_sched_barrier(0);
    __builtin_amdgcn_s_barrier();          // tile t fully in LDS for all waves
    __builtin_amdgcn_sched_barrier(0);

    const int lb = cb * 4096;
    bf16x8 af[4], bfr[4];
    #pragma unroll
    for (int m = 0; m < 4; ++m)
      af[m] = *(const bf16x8*)&sh_a[lb + (wm + m*16 + (lane & 15))*32 + (lane >> 4)*8];
    #pragma unroll
    for (int n = 0; n < 4; ++n)
      bfr[n] = *(const bf16x8*)&sh_b[lb + (wn + n*16 + (lane & 15))*32 + (lane >> 4)*8];
    __builtin_amdgcn_s_setprio(1);
    #pragma unroll
    for (int m = 0; m < 4; ++m)
      #pragma unroll
      for (int n = 0; n < 4; ++n)
        acc[m][n] = __builtin_amdgcn_mfma_f32_16x16x32_bf16(af[m], bfr[n], acc[m][n], 0, 0, 0);
    __builtin_amdgcn_s_setprio(0);
    if constexpr (FUSED) {
      bf16x8 cf[4];
      #pragma unroll
      for (int n = 0; n < 4; ++n)
        cf[n] = *(const bf16x8*)&sh_c[lb + (wn + n*16 + (lane & 15))*32 + (lane >> 4)*8];
      __builtin_amdgcn_s_setprio(1);
      #pragma unroll
      for (int m = 0; m < 4; ++m)
        #pragma unroll
        for (int n = 0; n < 4; ++n)
          acc2[m][n] = __builtin_amdgcn_mfma_f32_16x16x32_bf16(af[m], cf[n], acc2[m][n], 0, 0, 0);
      __builtin_amdgcn_s_setprio(0);
    }
    __builtin_amdgcn_sched_barrier(0);
    __builtin_amdgcn_s_barrier();          // all waves done reading buf cb
  }

  const int rq = (lane >> 4) * 4;
  const int cl = lane & 15;

  if constexpr (EPI == 0) {
    bf16* q_p = (bf16*)o0; bf16* k_p = (bf16*)o1; bf16* v_p = (bf16*)o2;
    const float* rope = (const float*)a0;
    int sec = (n0 + wn) >> 10;             // 0=q, 1=k, 2=v
    int h   = ((n0 + wn) & 1023) >> 6;
    const float qsc = (sec == 0) ? 0.18033688011112042f : 1.0f;  // 0.125*log2(e)
    #pragma unroll
    for (int m = 0; m < 4; ++m) {
      #pragma unroll
      for (int reg = 0; reg < 4; ++reg) {
        int r  = m0 + wm + m*16 + rq + reg;
        int b_ = r >> 11, s_ = r & 2047;
        int tile = s_ >> 5;
        size_t tb = ((size_t)(b_*NH + h) * 64 + tile) * 2048;  // 4KB tile base
        if (sec == 2) {
          int kvl = s_ & 31;
          int ks = kvl >> 4, hiv = (kvl >> 3) & 1, jv = kvl & 7;
          #pragma unroll
          for (int n = 0; n < 4; ++n) {
            int half = n >> 1;
            int qlv  = (n & 1) * 16 + cl;
            v_p[tb + (size_t)(ks*2 + half)*512 + (hiv*32 + qlv)*8 + jv] =
                (bf16)acc[m][n][reg];
          }
        } else {
          int qlt = s_ & 31;
          bf16* dst = (sec == 0 ? q_p : k_p);
          int lo = ((cl >> 3) * 32 + qlt) * 8 + (cl & 7);
          #pragma unroll
          for (int n = 0; n < 2; ++n) {
            int d1 = n*16 + cl;
            float c1 = rope[s_*64 + d1];
            float s1 = rope[s_*64 + 32 + d1];
            float x1 = acc[m][n][reg], x2 = acc[m][n+2][reg];
            dst[tb + (size_t)n*512 + lo]       = (bf16)((x1*c1 - x2*s1) * qsc);
            dst[tb + (size_t)(n+2)*512 + lo]   = (bf16)((x1*s1 + x2*c1) * qsc);
          }
        }
      }
    }
  } else if constexpr (EPI == 1) {
    float* op = (float*)o0;
    const float* rp = (const float*)a0;
    #pragma unroll
    for (int m = 0; m < 4; ++m)
      #pragma unroll
      for (int n = 0; n < 4; ++n)
        #pragma unroll
        for (int reg = 0; reg < 4; ++reg) {
          int r = m0 + wm + m*16 + rq + reg;
          int c = n0 + wn + n*16 + cl;
          op[(size_t)r*N + c] = acc[m][n][reg] + rp[(size_t)r*N + c];
        }
  } else if constexpr (EPI == 4) {
    float* op = (float*)o0 + (size_t)kb * M * N;
    #pragma unroll
    for (int m = 0; m < 4; ++m)
      #pragma unroll
      for (int n = 0; n < 4; ++n)
        #pragma unroll
        for (int reg = 0; reg < 4; ++reg) {
          int r = m0 + wm + m*16 + rq + reg;
          int c = n0 + wn + n*16 + cl;
          op[(size_t)r*N + c] = acc[m][n][reg];
        }
  } else if constexpr (EPI == 5) {
    bf16* op = (bf16*)o0;
    const float* bg = (const float*)a0;
    const float* bl = (const float*)a1;
    #pragma unroll
    for (int m = 0; m < 4; ++m)
      #pragma unroll
      for (int n = 0; n < 4; ++n)
        #pragma unroll
        for (int reg = 0; reg < 4; ++reg) {
          int r = m0 + wm + m*16 + rq + reg;
          int c = n0 + wn + n*16 + cl;
          float gv = acc[m][n][reg] + bg[c];
          float lv = acc2[m][n][reg] + bl[c];
          float s  = 1.f / (1.f + __expf(-gv));
          op[(size_t)r*N + c] = (bf16)(s * lv);
        }
  }
}

// ---------------- fused attention (no-max softmax, fragment-layout inputs) -
// QF,KF,VF: fragment-ordered (see EPI 0; Q pre-scaled by 0.125*log2e).
// Block = 128 q-rows x 4 waves, kv loop over 64 tiles of 32.
// Double-buffered LDS staging: raw s_barrier + counted vmcnt(2) so next
// tile's global_load_lds stays in flight across the barrier (T3/T4).
__global__ void __launch_bounds__(256) attn_kernel(
    const bf16* __restrict__ qf_g, const bf16* __restrict__ kf_g,
    const bf16* __restrict__ vf_g, bf16* __restrict__ ao_g) {
  __shared__ __align__(16) bf16 lds_k[2*2048];
  __shared__ __align__(16) bf16 lds_v[2*2048];
  const int tid  = threadIdx.x;
  const int lane = tid & 63;
  const int qw   = tid >> 6;      // wave's 32-row q group (0..3)
  const int hi   = lane >> 5;
  const int ql   = lane & 31;
  const int bh   = blockIdx.y;
  const int b_   = bh >> 4, h = bh & 15;
  const int q0   = blockIdx.x * 128 + qw * 32;
  const int qt   = blockIdx.x * 4 + qw;

  const bf16* qtile = qf_g + ((size_t)bh*64 + qt) * 2048;
  const bf16* kbase = kf_g + (size_t)bh * 64 * 2048;
  const bf16* vbase = vf_g + (size_t)bh * 64 * 2048;

  bf16x8 qf[4];
  #pragma unroll
  for (int ds = 0; ds < 4; ++ds)
    qf[ds] = *(const bf16x8*)&qtile[ds*512 + lane*8];

  f32x16 o0 = {}, o1 = {};
  float lrun = 0.f;

  // prologue: stage tile 0 into buffer 0
  gload16(kbase + tid*8, &lds_k[tid*8]);
  gload16(vbase + tid*8, &lds_v[tid*8]);

  for (int t = 0; t < 64; ++t) {
    const int cur = (t & 1) * 2048;
    if (t < 63) {
      const int nxt = 2048 - cur;
      gload16(kbase + (size_t)(t+1)*2048 + tid*8, &lds_k[nxt + tid*8]);
      gload16(vbase + (size_t)(t+1)*2048 + tid*8, &lds_v[nxt + tid*8]);
      asm volatile("s_waitcnt vmcnt(2)" ::: "memory");   // drain tile t only
    } else {
      asm volatile("s_waitcnt vmcnt(0)" ::: "memory");
    }
    __builtin_amdgcn_sched_barrier(0);
    __builtin_amdgcn_s_barrier();          // tile t visible to all waves
    __builtin_amdgcn_sched_barrier(0);

    f32x16 st = {};
    __builtin_amdgcn_s_setprio(1);
    #pragma unroll
    for (int ds = 0; ds < 4; ++ds) {
      bf16x8 kf = *(const bf16x8*)&lds_k[cur + ds*512 + lane*8];
      st = __builtin_amdgcn_mfma_f32_32x32x16_bf16(kf, qf[ds], st, 0, 0, 0);
    }
    __builtin_amdgcn_s_setprio(0);
    // st[reg] = (S*0.125*log2e)^T[k = (reg&3)+8*(reg>>2)+4*hi + t*32][q = ql]
    float p[16];
    float psum = 0.f;
    #pragma unroll
    for (int r = 0; r < 16; ++r) { p[r] = __builtin_amdgcn_exp2f(st[r]); psum += p[r]; }
    lrun += psum;                           // own half only; cross-half after loop

    uint32_t w0 = pkbf(p[0],p[1]),   w1 = pkbf(p[2],p[3]);
    uint32_t w2 = pkbf(p[4],p[5]),   w3 = pkbf(p[6],p[7]);
    uint32_t w4 = pkbf(p[8],p[9]),   w5 = pkbf(p[10],p[11]);
    uint32_t w6 = pkbf(p[12],p[13]), w7 = pkbf(p[14],p[15]);
    // half-wave transpose: a' = (aL,bL), b' = (aH,bH)
    asm("v_permlane32_swap_b32 %0, %1" : "+v"(w0), "+v"(w2));
    asm("v_permlane32_swap_b32 %0, %1" : "+v"(w1), "+v"(w3));
    asm("v_permlane32_swap_b32 %0, %1" : "+v"(w4), "+v"(w6));
    asm("v_permlane32_swap_b32 %0, %1" : "+v"(w5), "+v"(w7));

    __builtin_amdgcn_s_setprio(1);
    {
      union { u32x4 u; bf16x8 b; } pu;
      u32x4 pwa = {w0, w1, w2, w3};
      pu.u = pwa;
      bf16x8 v0 = *(const bf16x8*)&lds_v[cur + 0*512 + lane*8];
      bf16x8 v1 = *(const bf16x8*)&lds_v[cur + 1*512 + lane*8];
      o0 = __builtin_amdgcn_mfma_f32_32x32x16_bf16(v0, pu.b, o0, 0, 0, 0);
      o1 = __builtin_amdgcn_mfma_f32_32x32x16_bf16(v1, pu.b, o1, 0, 0, 0);
      u32x4 pwb = {w4, w5, w6, w7};
      pu.u = pwb;
      bf16x8 v2 = *(const bf16x8*)&lds_v[cur + 2*512 + lane*8];
      bf16x8 v3 = *(const bf16x8*)&lds_v[cur + 3*512 + lane*8];
      o0 = __builtin_amdgcn_mfma_f32_32x32x16_bf16(v2, pu.b, o0, 0, 0, 0);
      o1 = __builtin_amdgcn_mfma_f32_32x32x16_bf16(v3, pu.b, o1, 0, 0, 0);
    }
    __builtin_amdgcn_s_setprio(0);

    __builtin_amdgcn_sched_barrier(0);
    __builtin_amdgcn_s_barrier();          // all waves done reading buf cur
    __builtin_amdgcn_sched_barrier(0);
  }

  lrun += __shfl_xor(lrun, 32);
  float inv = 1.f / lrun;
  bf16* aop = ao_g + ((size_t)(b_*SSEQ) + q0 + ql) * DIMN + h*HD;
  #pragma unroll
  for (int g = 0; g < 4; ++g) {
    int dbase = 8*g + 4*hi;
    bf16x4 w0 = {(bf16)(o0[4*g]*inv), (bf16)(o0[4*g+1]*inv),
                 (bf16)(o0[4*g+2]*inv), (bf16)(o0[4*g+3]*inv)};
    *(bf16x4*)&aop[dbase] = w0;
    bf16x4 w1 = {(bf16)(o1[4*g]*inv), (bf16)(o1[4*g+1]*inv),
                 (bf16)(o1[4*g+2]*inv), (bf16)(o1[4*g+3]*inv)};
    *(bf16x4*)&aop[32 + dbase] = w1;
  }
}

// ---------------------------------------------------------------------------
// Workspace layout (bytes), max footprint 126,353,408:
//   wt   [0,        8388608)   8MB  weight^T staging (w_qkv/w_ao/w_gate/w_ffo)
//   rope [8388608,  8912896)   0.5MB
//   xb   [8912896, 17301504)   8MB  x bf16; reused as AO after attn
//   qkv  [17301504,42467328)  24MB  QF/KF/VF fragment layouts
//   P1   [17301504,50855936)  32MB  out-proj split-2 partials (qkv dead)
//   wt2  [50855936,59244544)   8MB  w_lin^T (during fused FFN1)
//   h1b  [84410368,92798976)   8MB  rmsnorm1 bf16 out
//   ffb  [8912896, 42467328)  32MB  swiglu out (ao/qkv/P1 dead)
//   P2   [42467328,109576192) 64MB  ff-out split-4 partials (wt2/h1b dead)
//   h1f  [109576192,126353408)16MB  rmsnorm1 f32 out (long-lived resid)
extern "C" void kernel_launch(void* const* d_in, const int* in_sizes, int n_in,
                              void* d_out, int out_size, void* d_ws, size_t ws_size,
                              hipStream_t stream) {
  const float* x      = (const float*)d_in[0];
  const float* w_qkv  = (const float*)d_in[1];
  const float* w_ao   = (const float*)d_in[2];
  const float* w_gate = (const float*)d_in[3];
  const float* b_gate = (const float*)d_in[4];
  const float* w_lin  = (const float*)d_in[5];
  const float* b_lin  = (const float*)d_in[6];
  const float* w_ffo  = (const float*)d_in[7];
  const float* scale1 = (const float*)d_in[8];
  const float* scale2 = (const float*)d_in[9];
  float* out = (float*)d_out;
  (void)ws_size; (void)in_sizes; (void)n_in; (void)out_size;

  uint8_t* ws = (uint8_t*)d_ws;
  bf16*  wt_ws   = (bf16*) (ws + 0);
  float* rope_ws = (float*)(ws + 8388608);
  bf16*  xb_ws   = (bf16*) (ws + 8912896);
  bf16*  ao_ws   = (bf16*) (ws + 8912896);    // reuse XB
  bf16*  q_ws    = (bf16*) (ws + 17301504);
  bf16*  k_ws    = (bf16*) (ws + 25690112);
  bf16*  v_ws    = (bf16*) (ws + 34078720);
  float* p1_ws   = (float*)(ws + 17301504);   // 32MB, reuse QKV region
  bf16*  wt2_ws  = (bf16*) (ws + 50855936);   // 8MB  w_lin^T
  bf16*  h1b_ws  = (bf16*) (ws + 84410368);   // 8MB
  bf16*  ffb_ws  = (bf16*) (ws + 8912896);    // 32MB, reuse XB/AO + QKV head
  float* p2_ws   = (float*)(ws + 42467328);   // 64MB, reuse wt2/h1b + gap
  float* h1f_ws  = (float*)(ws + 109576192);  // 16MB

  // 1. rope table + x cast + w_qkv^T
  rope_table_kernel<<<256, 256, 0, stream>>>(rope_ws);
  cast_f32_bf16<<<4096, 256, 0, stream>>>(x, xb_ws, MROWS*DIMN/4);
  transpose_cast_f32_bf16<<<dim3(3*DIMN/32, DIMN/32), dim3(32,8), 0, stream>>>(w_qkv, wt_ws, DIMN, 3*DIMN);
  // 2. QKV gemm + rope epilogue -> fragment-layout QF/KF/VF (Q pre-scaled)
  gemm_bt<0><<<dim3(24, 32), 256, 0, stream>>>(xb_ws, wt_ws, MROWS, 3*DIMN, DIMN,
                                               q_ws, k_ws, v_ws, rope_ws, nullptr);
  // 3. attention (double-buffered KV staging, counted vmcnt)
  attn_kernel<<<dim3(16, 32), 256, 0, stream>>>(q_ws, k_ws, v_ws, ao_ws);
  // 4. out-proj, split-K=2 -> f32 partials (resid folded into rmsnorm)
  transpose_cast_f32_bf16<<<dim3(DIMN/32, DIMN/32), dim3(32,8), 0, stream>>>(w_ao, wt_ws, DIMN, DIMN);
  gemm_bt<4><<<dim3(8, 32, 2), 256, 0, stream>>>(ao_ws, wt_ws, MROWS, DIMN, DIMN,
                                                 p1_ws, nullptr, nullptr, nullptr, nullptr);
  // 5. rmsnorm1 over (p0+p1+x) -> f32 + bf16
  rmsnorm_sum_kernel<2><<<MROWS, 256, 0, stream>>>(p1_ws, x, scale1, h1f_ws, h1b_ws);
  // 6. fused FFN1: sigmoid(h1b@w_gate + bg) * (h1b@w_lin + bl) -> bf16
  transpose_cast_f32_bf16<<<dim3(FFN/32, DIMN/32), dim3(32,8), 0, stream>>>(w_gate, wt_ws, DIMN, FFN);
  transpose_cast_f32_bf16<<<dim3(FFN/32, DIMN/32), dim3(32,8), 0, stream>>>(w_lin, wt2_ws, DIMN, FFN);
  gemm_bt<5><<<dim3(32, 32), 256, 0, stream>>>(h1b_ws, wt_ws, MROWS, FFN, DIMN,
                                               ffb_ws, wt2_ws, nullptr, b_gate, b_lin);
  // 7. ff-out gemm, split-K=4 -> f32 partials
  transpose_cast_f32_bf16<<<dim3(DIMN/32, FFN/32), dim3(32,8), 0, stream>>>(w_ffo, wt_ws, FFN, DIMN);
  gemm_bt<4><<<dim3(8, 32, 4), 256, 0, stream>>>(ffb_ws, wt_ws, MROWS, DIMN, FFN,
                                                 p2_ws, nullptr, nullptr, nullptr, nullptr);
  // 8. rmsnorm2 over (p0+p1+p2+p3+h1f) -> output (f32)
  rmsnorm_sum_kernel<4><<<MROWS, 256, 0, stream>>>(p2_ws, h1f_ws, scale2, out, nullptr);
}